// Round 12
// baseline (212.105 us; speedup 1.0000x reference)
//
#include <hip/hip_runtime.h>
#include <math.h>
#include <float.h>

// Problem constants (B=32, C=32, H=W=32, V=4096)
#define BS    32
#define CH    32
#define HH    32
#define VV    4096
#define FELEMS (BS*CH*HH*HH)   // 1048576
#define NROWS_TOTAL 43680      // sum over scales of B*pn*pn

typedef unsigned short ushort_t;
typedef unsigned long long u64_t;
typedef _Float16 half_t;
typedef __attribute__((ext_vector_type(8))) _Float16 half8;
typedef __attribute__((ext_vector_type(4))) float floatx4;

// 2-way fp16 split: x ~= h + l, residual <= 2^-22 |x|
__device__ inline void split2(float x, half_t* h, half_t* l) {
    half_t hh = (half_t)x;
    float r = x - (float)hh;
    *h = hh;
    *l = (half_t)r;
}

// fp32 -> sortable-descending key32 (bigger score => smaller key)
__device__ inline unsigned score_key32(float s) {
    unsigned u = __builtin_bit_cast(unsigned, s);
    unsigned m = (u & 0x80000000u) ? ~u : (u | 0x80000000u);  // monotone asc
    return ~m;                                                 // desc
}

// ---------------------------------------------------------------------------
// prep (grid 1024x256): emb fp16-split + nesqh, zero f_hat output + hits +
// zp pool-accumulators, init pk keys to +inf, split conv weights into
// MFMA-A-fragment-ordered global buffers (lane col=co, 8 ci per quad),
// AND pool si=0 with per-block sumsq partials.
__global__ __launch_bounds__(256) void prep_kernel(const float* __restrict__ f,
                                                   const float* __restrict__ emb,
                                                   const float* __restrict__ phw,
                                                   half_t* __restrict__ whi,
                                                   half_t* __restrict__ wlo,
                                                   half_t* __restrict__ ehi,
                                                   half_t* __restrict__ elo,
                                                   float* __restrict__ nesqh,
                                                   float* __restrict__ hits,
                                                   float* __restrict__ laccp,
                                                   half_t* __restrict__ zhi,
                                                   half_t* __restrict__ zlo,
                                                   u64_t* __restrict__ pk,
                                                   float* __restrict__ zpbase,
                                                   float* __restrict__ dout) {
    int gid = blockIdx.x * 256 + threadIdx.x;      // 262144 threads
    float4 z4 = {0.f, 0.f, 0.f, 0.f};
    *(float4*)(dout + (size_t)gid * 4) = z4;
    if (gid < VV) hits[gid] = 0.f;
    if (gid < NROWS_TOTAL) pk[gid] = ~0ull;        // +inf keys
    for (int j = gid; j < 348160; j += 262144) zpbase[j] = 0.f;  // pool accum
    if (gid < 36864) {
        // W split-frag pack: idx = ((((phi*2+mt)*9+tau)*4+q)*16+c)*8+k
        int k = gid & 7, c = (gid >> 3) & 15, q = (gid >> 7) & 3;
        int t2 = gid >> 9;                 // 0..71
        int tau = t2 % 9, m2 = t2 / 9;
        int mt = m2 & 1, phi = m2 >> 1;
        int co = mt * 16 + c, ci = q * 8 + k;
        float w = phw[((size_t)(phi * 32 + co) * 32 + ci) * 9 + tau];
        half_t h, l; split2(w, &h, &l);
        whi[gid] = h; wlo[gid] = l;
    }
    if (gid < VV) {
        int v = gid;
        const float* ep = emb + (size_t)v * CH;
        float s = 0.f;
        half_t h[CH], l[CH];
#pragma unroll
        for (int i = 0; i < CH; i++) {
            float e = ep[i];
            s = fmaf(e, e, s);
            split2(e, &h[i], &l[i]);
        }
        nesqh[v] = -0.5f * s;
#pragma unroll
        for (int q = 0; q < 4; q++) {
            half8 H, L;
#pragma unroll
            for (int k = 0; k < 8; k++) {
                H[k] = h[q * 8 + k];
                L[k] = l[q * 8 + k];
            }
            *(half8*)(ehi + (size_t)v * CH + q * 8) = H;
            *(half8*)(elo + (size_t)v * CH + q * 8) = L;
        }
    }

    // pool si=0: pair = blockIdx.x = b*32 + c; base = f + pair*1024
    const int pair = blockIdx.x;
    const float* base = f + (size_t)pair * 1024;
    float s = 0.f, s2 = 0.f;
    for (int p = threadIdx.x; p < 1024; p += 256) {
        float v = base[p];
        s += v;
        s2 = fmaf(v, v, s2);
    }
    __shared__ float sh[256], sh2[256];
    sh[threadIdx.x] = s;
    sh2[threadIdx.x] = s2;
    __syncthreads();
    for (int o = 128; o > 0; o >>= 1) {
        if (threadIdx.x < o) {
            sh[threadIdx.x]  += sh[threadIdx.x + o];
            sh2[threadIdx.x] += sh2[threadIdx.x + o];
        }
        __syncthreads();
    }
    if (threadIdx.x == 0) {
        split2(sh[0] * (1.0f / 1024.0f), &zhi[pair], &zlo[pair]);
        laccp[pair] = sh2[0];      // deterministic partial, summed in finalize
    }
}

// ---------------------------------------------------------------------------
// 3-MFMA fp16 score chain for one 16-row group vs one 16-code tile
// score = z.e - 0.5|e|^2 = ah.bh + ah.bl + al.bh  (al.bl <= 2^-22 dropped)
__device__ inline floatx4 score_chain(half8 ah, half8 al,
                                      half8 bh, half8 bl, floatx4 ehv) {
    floatx4 acc;
    acc = __builtin_amdgcn_mfma_f32_16x16x32_f16(ah, bh, ehv, 0, 0, 0);
    acc = __builtin_amdgcn_mfma_f32_16x16x32_f16(ah, bl, acc, 0, 0, 0);
    acc = __builtin_amdgcn_mfma_f32_16x16x32_f16(al, bh, acc, 0, 0, 0);
    return acc;
}

__device__ inline void sel4(const floatx4& acc, int v, float* best, int* bidx) {
#pragma unroll
    for (int r = 0; r < 4; r++) {
        // strict >: lane-local scan is increasing v -> keeps lowest v on tie
        if (acc[r] > best[r]) { best[r] = acc[r]; bidx[r] = v; }
    }
}

// argmin core (r7-proven decomposition: 4 waves share rows, scan disjoint
// t-ranges; r8's row-split shared-t variant REGRESSED). r11: last iteration
// PEELED so the in-loop prefetch address is affine in t — the old
// tn=min(t+1,tend-1) clamp forced the compiler to recompute the full 64-bit
// address chain every tile instead of strength-reducing to increments.
// Winner per row merged cross-block via packed-key atomicMin (max score,
// lowest idx on tie == jnp.argmin).
template <int RT, int TPW>
__device__ inline void argmin_body(const half8* a1, const half8* a2,
                                   const half_t* __restrict__ ehi,
                                   const half_t* __restrict__ elo,
                                   const float* __restrict__ nesqh,
                                   u64_t* __restrict__ pk, int row0, int t0) {
    const int tid  = threadIdx.x;
    const int wv   = tid >> 6;
    const int lane = tid & 63;
    const int col  = lane & 15;
    const int quad = lane >> 4;

    float best[RT][4];
    int   bidx[RT][4];
#pragma unroll
    for (int rt = 0; rt < RT; rt++)
#pragma unroll
        for (int r = 0; r < 4; r++) { best[rt][r] = -FLT_MAX; bidx[rt][r] = 0; }

    int t = t0 + wv * TPW;
    const int tend = t + TPW;

    // prefetch tile t
    size_t eoff = ((size_t)((t << 4) + col) << 5) + (quad << 3);
    half8 nb1 = *(const half8*)(ehi + eoff);
    half8 nb2 = *(const half8*)(elo + eoff);
    float neh = nesqh[(t << 4) + col];

    floatx4 acc[RT];
    int vprev = 0;
    if (RT > 1) acc[RT - 1] = floatx4{-FLT_MAX, -FLT_MAX, -FLT_MAX, -FLT_MAX};

    auto consume = [&](const half8 b1, const half8 b2,
                       const floatx4 ehv, const int vcur) {
        if (RT == 1) {
            acc[0] = score_chain(a1[0], a2[0], b1, b2, ehv);
            sel4(acc[0], vcur, best[0], bidx[0]);
        } else {
            acc[0] = score_chain(a1[0], a2[0], b1, b2, ehv);
            sel4(acc[RT - 1], vprev, best[RT - 1], bidx[RT - 1]);  // deferred
#pragma unroll
            for (int rt = 1; rt < RT; rt++) {
                acc[rt] = score_chain(a1[rt], a2[rt], b1, b2, ehv);
                sel4(acc[rt - 1], vcur, best[rt - 1], bidx[rt - 1]);
            }
            vprev = vcur;
        }
    };

    for (; t < tend - 1; t++) {
        const half8 b1 = nb1, b2 = nb2;
        const floatx4 ehv = {neh, neh, neh, neh};
        const int vcur = (t << 4) + col;
        // prefetch t+1 (UNCLAMPED — affine, strength-reducible)
        const size_t eoff2 = ((size_t)(((t + 1) << 4) + col) << 5) + (quad << 3);
        nb1 = *(const half8*)(ehi + eoff2);
        nb2 = *(const half8*)(elo + eoff2);
        neh = nesqh[((t + 1) << 4) + col];
        consume(b1, b2, ehv, vcur);
    }
    {   // peeled final iteration (no prefetch)
        const floatx4 ehv = {neh, neh, neh, neh};
        consume(nb1, nb2, ehv, (t << 4) + col);
    }
    if (RT > 1) sel4(acc[RT - 1], vprev, best[RT - 1], bidx[RT - 1]);

    // reduce across the 16 cols (v within tile) of each quad group
#pragma unroll
    for (int m = 1; m < 16; m <<= 1) {
#pragma unroll
        for (int rt = 0; rt < RT; rt++)
#pragma unroll
            for (int r = 0; r < 4; r++) {
                float s2 = __shfl_xor(best[rt][r], m, 64);
                int   v2 = __shfl_xor(bidx[rt][r], m, 64);
                if (s2 > best[rt][r] ||
                    (s2 == best[rt][r] && v2 < bidx[rt][r])) {
                    best[rt][r] = s2; bidx[rt][r] = v2;
                }
            }
    }

    __shared__ float sbs[4 * RT * 16];
    __shared__ int   sbi[4 * RT * 16];
    if (col == 0) {
#pragma unroll
        for (int rt = 0; rt < RT; rt++)
#pragma unroll
            for (int r = 0; r < 4; r++) {
                int row = rt * 16 + (quad << 2) + r;
                sbs[wv * RT * 16 + row] = best[rt][r];
                sbi[wv * RT * 16 + row] = bidx[rt][r];
            }
    }
    __syncthreads();
    if (tid < RT * 16) {
        float s = sbs[tid];
        int   v = sbi[tid];
        for (int w = 1; w < 4; w++) {
            float s2 = sbs[w * RT * 16 + tid];
            int   v2 = sbi[w * RT * 16 + tid];
            if (s2 > s || (s2 == s && v2 < v)) { s = s2; v = v2; }
        }
        u64_t key = ((u64_t)score_key32(s) << 32) | (unsigned)v;
        atomicMin(pk + row0 + tid, key);
    }
}

// generic stage: z-splits from memory (si=0 only). grid = (nRowBlocks, VS)
template <int RT, int VS>
__global__ __launch_bounds__(256) void argmin_stage(const half_t* __restrict__ zhi,
                                                    const half_t* __restrict__ zlo,
                                                    const half_t* __restrict__ ehi,
                                                    const half_t* __restrict__ elo,
                                                    const float* __restrict__ nesqh,
                                                    u64_t* __restrict__ pk) {
    const int lane = threadIdx.x & 63;
    const int col  = lane & 15;
    const int quad = lane >> 4;
    const int row0 = blockIdx.x * (16 * RT);

    half8 a1[RT], a2[RT];
#pragma unroll
    for (int rt = 0; rt < RT; rt++) {
        size_t off = ((size_t)(row0 + rt * 16 + col) << 5) + (quad << 3);
        a1[rt] = *(const half8*)(zhi + off);
        a2[rt] = *(const half8*)(zlo + off);
    }
    argmin_body<RT, 64 / VS>(a1, a2, ehi, elo, nesqh, pk,
                             row0, (int)blockIdx.y * (256 / VS));
}

// zp stage (si=1..4): pooled z arrives fully accumulated (conv epilogue
// atomicAdds into a zeroed per-scale slice). Scale by exact pow2 1/ps'^2,
// split2 in-register.
template <int RT, int VS, int PN>
__global__ __launch_bounds__(256) void argmin_zp(const float* __restrict__ zp,
                                                 const half_t* __restrict__ ehi,
                                                 const half_t* __restrict__ elo,
                                                 const float* __restrict__ nesqh,
                                                 u64_t* __restrict__ pk) {
    const int lane = threadIdx.x & 63;
    const int col  = lane & 15;
    const int quad = lane >> 4;
    const int row0 = blockIdx.x * (16 * RT);
    constexpr int PSP = 32 / PN;
    const float scale = 1.0f / (float)(PSP * PSP);

    half8 a1[RT], a2[RT];
#pragma unroll
    for (int rt = 0; rt < RT; rt++) {
        const float* p = zp + (size_t)(row0 + rt * 16 + col) * CH + (quad << 3);
        float4 v0 = *(const float4*)p;
        float4 v1 = *(const float4*)(p + 4);
        float s[8] = {v0.x, v0.y, v0.z, v0.w, v1.x, v1.y, v1.z, v1.w};
#pragma unroll
        for (int k = 0; k < 8; k++) {
            half_t h, l;
            split2(s[k] * scale, &h, &l);
            a1[rt][k] = h; a2[rt][k] = l;
        }
    }
    argmin_body<RT, 64 / VS>(a1, a2, ehi, elo, nesqh, pk,
                             row0, (int)blockIdx.y * (256 / VS));
}

// si=5 fused: pool is identity (pn=32) -> split2 straight from frest.
// r11: grid = (512, 4) — 2048 blocks = 8 blocks/CU (was 4: grid-limited at
// Occupancy 30% despite VGPR=56/LDS=2KB allowing 8). TPW=16.
__global__ __launch_bounds__(256) void argmin5_fused(const float* __restrict__ frest,
                                                     const half_t* __restrict__ ehi,
                                                     const half_t* __restrict__ elo,
                                                     const float* __restrict__ nesqh,
                                                     u64_t* __restrict__ pk) {
    const int lane = threadIdx.x & 63;
    const int col  = lane & 15;
    const int quad = lane >> 4;
    const int row0 = blockIdx.x * 64;   // RT=4

    half8 a1[4], a2[4];
#pragma unroll
    for (int rt = 0; rt < 4; rt++) {
        int n = row0 + rt * 16 + col;               // row = (b*32+i)*32+j
        int b = n >> 10, i = (n >> 5) & 31, j = n & 31;
        const float* p = frest + ((((size_t)(b * CH + quad * 8)) * HH + i) * HH + j);
#pragma unroll
        for (int k = 0; k < 8; k++) {
            half_t h, l;
            split2(p[(size_t)k * (HH * HH)], &h, &l);   // c stride = 1024
            a1[rt][k] = h; a2[rt][k] = l;
        }
    }
    argmin_body<4, 16>(a1, a2, ehi, elo, nesqh, pk,
                       row0, (int)blockIdx.y * 64);
}

// ---------------------------------------------------------------------------
// bicubic weights, a=-0.75, half-pixel, edge clamp (matches ref _bicubic_mat)
__device__ inline void cubic_w(float xs, int pn, int* ix, float* w) {
    const float a = -0.75f;
    float xf = floorf(xs);
    int x0 = (int)xf;
    float t = xs - xf;
#pragma unroll
    for (int j = -1; j <= 2; j++) {
        float d = fabsf(t - (float)j);
        float ww;
        if (d < 1.0f)      ww = ((a + 2.0f) * d - (a + 3.0f)) * d * d + 1.0f;
        else if (d < 2.0f) ww = ((a * d - 5.0f * a) * d + 8.0f * a) * d - 4.0f * a;
        else               ww = 0.0f;
        int xi = x0 + j;
        xi = xi < 0 ? 0 : (xi > pn - 1 ? pn - 1 : xi);
        ix[j + 1] = xi;
        w[j + 1]  = ww;
    }
}

// ---------------------------------------------------------------------------
// MFMA conv: dst = src - (0.5*h + 0.5*(conv3x3(h)+bias)), h = bicubic
// upsample, fp16-split into LDS, consumed by 16x16x32 f16 MFMA 3-chains
// (r7-verified fragment convention; r9 LDS window tables; r10 512x512 shape,
// neutral vs 256x1024 — kept).
template <int PN, int PN_NEXT>
__global__ __launch_bounds__(512) void conv_mfma_kernel(const u64_t* __restrict__ pk,
                                                        const float* __restrict__ emb,
                                                        const half_t* __restrict__ whi,
                                                        const half_t* __restrict__ wlo,
                                                        const float* __restrict__ bias,
                                                        const float* __restrict__ src,
                                                        float* __restrict__ dst,
                                                        float* __restrict__ zp) {
    constexpr int IYB = (PN <= 4) ? PN : 6;   // iy tap band (span<=5 here)
    const int t    = threadIdx.x;
    const int lane = t & 63, col = lane & 15, quad = lane >> 4;
    const int wid  = t >> 6;                  // 0..7
    const int Nt   = wid >> 1, mt = wid & 1;
    const int ty   = Nt >> 1, xh = Nt & 1;    // ty 0..1
    const int yt   = blockIdx.x & 15, b = blockIdx.x >> 4;
    const int y0   = yt * 2;

    __shared__ half8 Hhi8[544], Hlo8[544];    // 4*34*32 halves = 8704 B each
    __shared__ float cache[IYB][PN][32];      // emb rows, ch-minor
    __shared__ int   riy[4][4];               // iy - iy_lo per staged row
    __shared__ float rwy[4][4];
    __shared__ int   cxs[34][4];              // col windows (gx = cl-1)
    __shared__ float cws[34][4];
    half_t* Hhi = (half_t*)Hhi8;
    half_t* Hlo = (half_t*)Hlo8;

    const float scale = (float)PN / (float)HH;
    int iy_lo = 0;
    if (PN > 4) {
        int lo = (int)floorf(((float)(y0 - 1) + 0.5f) * scale - 0.5f) - 1;
        lo = lo < 0 ? 0 : lo;
        lo = lo > PN - IYB ? PN - IYB : lo;
        iy_lo = lo;
    }

    // emb gather -> cache (float4 per 4ch; winner idx straight from pk, L2)
    const u64_t* pkb = pk + b * PN * PN;
    for (int i = t; i < IYB * PN * 8; i += 512) {
        int chg = i & 7, cell = i >> 3;
        int ix = cell % PN, iyb = cell / PN;
        int idx = (int)(unsigned)(pkb[(iy_lo + iyb) * PN + ix] & 0xFFFFFFFFull);
        *(float4*)&cache[iyb][ix][chg * 4] =
            *(const float4*)(emb + (size_t)idx * CH + chg * 4);
    }
    // bicubic window tables (disjoint thread ranges, concurrent with gather)
    if (t < 4) {
        int iy[4]; float wy[4];
        cubic_w(((float)(y0 - 1 + t) + 0.5f) * scale - 0.5f, PN, iy, wy);
#pragma unroll
        for (int a = 0; a < 4; a++) { riy[t][a] = iy[a] - iy_lo; rwy[t][a] = wy[a]; }
    }
    if (t >= 64 && t < 98) {
        int cl = t - 64;                  // col 0..33, gx = cl-1
        int ix[4]; float wx[4];
        cubic_w(((float)(cl - 1) + 0.5f) * scale - 0.5f, PN, ix, wx);
#pragma unroll
        for (int a = 0; a < 4; a++) { cxs[cl][a] = ix[a]; cws[cl][a] = wx[a]; }
    }
    __syncthreads();

    // bicubic staging -> H fp16-split (4 ch per iter; windows from LDS,
    // values & fma order bit-identical). 136 cells (4 rows x 34 cols) x 8.
    for (int i = t; i < 1088; i += 512) {
        int chg = i & 7, cell = i >> 3;
        int xs = cell % 34, row = cell / 34;     // row 0..3
        int gy = y0 - 1 + row, gx = xs - 1;
        float s0 = 0.f, s1 = 0.f, s2 = 0.f, s3 = 0.f;
        if ((unsigned)gy < 32u && (unsigned)gx < 32u) {
#pragma unroll
            for (int a = 0; a < 4; a++) {
                const int iyb = riy[row][a];
                const float wya = rwy[row][a];
                float r0 = 0.f, r1 = 0.f, r2 = 0.f, r3 = 0.f;
#pragma unroll
                for (int b2 = 0; b2 < 4; b2++) {
                    const float4 tv = *(const float4*)&cache[iyb][cxs[xs][b2]][chg * 4];
                    const float wxb = cws[xs][b2];
                    r0 = fmaf(tv.x, wxb, r0);
                    r1 = fmaf(tv.y, wxb, r1);
                    r2 = fmaf(tv.z, wxb, r2);
                    r3 = fmaf(tv.w, wxb, r3);
                }
                s0 = fmaf(r0, wya, s0);
                s1 = fmaf(r1, wya, s1);
                s2 = fmaf(r2, wya, s2);
                s3 = fmaf(r3, wya, s3);
            }
        }
        const int ho = cell * 32 + chg * 4;
        half_t h, l;
        split2(s0, &h, &l); Hhi[ho + 0] = h; Hlo[ho + 0] = l;
        split2(s1, &h, &l); Hhi[ho + 1] = h; Hlo[ho + 1] = l;
        split2(s2, &h, &l); Hhi[ho + 2] = h; Hlo[ho + 2] = l;
        split2(s3, &h, &l); Hhi[ho + 3] = h; Hlo[ho + 3] = l;
    }
    __syncthreads();

    // 9-tap MFMA accumulation; C-init = bias per output row (co)
    const float4 bv = *(const float4*)(bias + mt * 16 + quad * 4);
    floatx4 acc = {bv.x, bv.y, bv.z, bv.w};
#pragma unroll
    for (int tau = 0; tau < 9; tau++) {
        const int dy = tau / 3, dx = tau % 3;
        const int woff = (mt * 9 + tau) * 512 + quad * 128 + col * 8;
        const half8 wh = *(const half8*)(whi + woff);
        const half8 wl = *(const half8*)(wlo + woff);
        const int hoff = ((ty + dy) * 34 + xh * 16 + dx + col) * 32 + quad * 8;
        const half8 hh = *(const half8*)(Hhi + hoff);
        const half8 hl = *(const half8*)(Hlo + hoff);
        acc = __builtin_amdgcn_mfma_f32_16x16x32_f16(wh, hh, acc, 0, 0, 0);
        acc = __builtin_amdgcn_mfma_f32_16x16x32_f16(wh, hl, acc, 0, 0, 0);
        acc = __builtin_amdgcn_mfma_f32_16x16x32_f16(wl, hh, acc, 0, 0, 0);
    }

    // epilogue: residual + store; lane owns pix (y0+ty, xh*16+col), 4 co's
    const int x = xh * 16 + col, y = y0 + ty;
    const int hcell = ((ty + 1) * 34 + (x + 1)) * 32;
    float pv[4];
#pragma unroll
    for (int r = 0; r < 4; r++) {
        const int c = mt * 16 + quad * 4 + r;
        const float hc = (float)Hhi[hcell + c] + (float)Hlo[hcell + c];
        const size_t off = (((size_t)(b * CH + c)) * HH + y) * HH + x;
        const float dv = src[off] - (0.5f * hc + 0.5f * acc[r]);
        dst[off] = dv;
        pv[r] = dv;
    }

    if constexpr (PN_NEXT != 0) {
        constexpr int PSP = 32 / PN_NEXT;        // 16/8/4/2 (<=16: in-wave x)
#pragma unroll
        for (int m = 1; m < PSP; m <<= 1)        // col bits only, stays in quad
#pragma unroll
            for (int r = 0; r < 4; r++) pv[r] += __shfl_xor(pv[r], m, 64);
        if ((col & (PSP - 1)) == 0) {
            const int wx = x / PSP, wy = y / PSP;
#pragma unroll
            for (int r = 0; r < 4; r++) {
                const int c = mt * 16 + quad * 4 + r;
                atomicAdd(zp + ((size_t)((b * PN_NEXT + wy) * PN_NEXT + wx)) * CH + c,
                          pv[r]);
            }
        }
    }
}

// ---------------------------------------------------------------------------
// hits bincount over all scales' packed winners (multi-block, parallel —
// r3 lesson: single-block LDS-hist finalize was a 60us serial tail)
__global__ __launch_bounds__(256) void bincount_kernel(const u64_t* __restrict__ pk,
                                                       float* __restrict__ hits, int n) {
    int i = blockIdx.x * 256 + threadIdx.x;
    if (i < n) {
        int idx = (int)(unsigned)(pk[i] & 0xFFFFFFFFull);
        atomicAdd(&hits[idx], 1.0f);
    }
}

// ---------------------------------------------------------------------------
// perplexity + loss finalize (single block; reads only 4096-entry hist +
// 1024 lacc partials = 20 KB)
__global__ __launch_bounds__(256) void finalize_kernel(const float* __restrict__ hits,
                                                       const float* __restrict__ laccp,
                                                       float* __restrict__ outs) {
    __shared__ float sh[256];
    int t = threadIdx.x;
    // total = NROWS_TOTAL exactly (each row contributes one hit)
    const float tot = (float)NROWS_TOTAL;
    float ent = 0.f;
    for (int v = t; v < VV; v += 256) {
        float p = hits[v] / tot;
        ent += p * logf(p + 1e-10f);
    }
    sh[t] = ent;
    __syncthreads();
    for (int o = 128; o > 0; o >>= 1) {
        if (t < o) sh[t] += sh[t + o];
        __syncthreads();
    }
    float entT = sh[0];            // valid for all after the synced tree
    __syncthreads();
    float ls = 0.f;
    for (int i = t; i < 1024; i += 256) ls += laccp[i];
    sh[t] = ls;
    __syncthreads();
    for (int o = 128; o > 0; o >>= 1) {
        if (t < o) sh[t] += sh[t + o];
        __syncthreads();
    }
    if (t == 0) {
        // loss = SN*(1+BETA)*mean(f^2) = 7.5 * sumsq / 1048576  (f_hat stays 0)
        outs[0] = 7.5f * sh[0] * (1.0f / (float)FELEMS);
        outs[1] = expf(-entT);
    }
}

// ---------------------------------------------------------------------------
extern "C" void kernel_launch(void* const* d_in, const int* in_sizes, int n_in,
                              void* d_out, int out_size, void* d_ws, size_t ws_size,
                              hipStream_t stream) {
    const float* f   = (const float*)d_in[0];   // (32,32,32,32)
    const float* emb = (const float*)d_in[1];   // (4096,32)
    const float* phw = (const float*)d_in[2];   // (4,32,32,3,3)
    const float* phb = (const float*)d_in[3];   // (4,32)
    float* out = (float*)d_out;                 // f_hat (1048576) + loss + perplexity

    float* ws      = (float*)d_ws;
    float* hits    = ws;                              // [0, 4096)
    float* laccp   = ws + 4096;                       // [4096, 5120) partials
    u64_t* pkbase  = (u64_t*)(ws + 8448);             // 43680 u64 -> [8448, 95808)
    float* frest   = ws + 95808;                      // [95808, 1144384)
    half_t* zhi    = (half_t*)(ws + 1144384);         // si=0 z-split (1024 used)
    half_t* zlo    = (half_t*)(ws + 1275456);
    float* nesqh   = ws + 1537600;                    // [1537600, 1541696)
    half_t* ehi    = (half_t*)(ws + 2590272);         // 131072 halves
    half_t* elo    = (half_t*)(ws + 2655808);         // ends 2721344
    float* zp      = ws + 2721344;                    // 348160 f -> ends 3069504
    half_t* whi    = (half_t*)(ws + 3069504);         // 36864 halves
    half_t* wlo    = (half_t*)(ws + 3087936);         // ends 3106368 (12.4 MB)

    // zp slices (zeroed once in prep; each written by exactly one conv)
    float* zp1 = zp;            // PN_NEXT=2:  4096
    float* zp2 = zp + 4096;     // PN_NEXT=4:  16384
    float* zp3 = zp + 20480;    // PN_NEXT=8:  65536
    float* zp4 = zp + 86016;    // PN_NEXT=16: 262144 -> total 348160

    prep_kernel<<<1024, 256, 0, stream>>>(f, emb, phw, whi, wlo, ehi, elo, nesqh,
                                          hits, laccp, zhi, zlo, pkbase, zp, out);

    const int pkoff[6] = {0, 32, 160, 672, 2720, 10912};
    const size_t WFP = 9216;                          // halves per phi frag-pack

    // si=0 (pn=1, sel=0)
    argmin_stage<1, 16><<<dim3(2, 16), 256, 0, stream>>>(zhi, zlo, ehi, elo, nesqh,
                                                         pkbase + pkoff[0]);
    conv_mfma_kernel<1, 2><<<512, 512, 0, stream>>>(pkbase + pkoff[0], emb,
                                                    whi + 0 * WFP, wlo + 0 * WFP,
                                                    phb + 0 * CH, f, frest, zp1);

    // si=1 (pn=2, sel=0)
    argmin_zp<1, 16, 2><<<dim3(8, 16), 256, 0, stream>>>(zp1, ehi, elo, nesqh,
                                                         pkbase + pkoff[1]);
    conv_mfma_kernel<2, 4><<<512, 512, 0, stream>>>(pkbase + pkoff[1], emb,
                                                    whi + 0 * WFP, wlo + 0 * WFP,
                                                    phb + 0 * CH, frest, frest, zp2);

    // si=2 (pn=4, sel=1)
    argmin_zp<1, 16, 4><<<dim3(32, 16), 256, 0, stream>>>(zp2, ehi, elo, nesqh,
                                                          pkbase + pkoff[2]);
    conv_mfma_kernel<4, 8><<<512, 512, 0, stream>>>(pkbase + pkoff[2], emb,
                                                    whi + 1 * WFP, wlo + 1 * WFP,
                                                    phb + 1 * CH, frest, frest, zp3);

    // si=3 (pn=8, sel=2)
    argmin_zp<1, 8, 8><<<dim3(128, 8), 256, 0, stream>>>(zp3, ehi, elo, nesqh,
                                                         pkbase + pkoff[3]);
    conv_mfma_kernel<8, 16><<<512, 512, 0, stream>>>(pkbase + pkoff[3], emb,
                                                     whi + 2 * WFP, wlo + 2 * WFP,
                                                     phb + 2 * CH, frest, frest, zp4);

    // si=4 (pn=16, sel=3): VS 4->8 (2048 blocks = 8/CU; was grid-limited)
    argmin_zp<2, 8, 16><<<dim3(256, 8), 256, 0, stream>>>(zp4, ehi, elo, nesqh,
                                                          pkbase + pkoff[4]);
    conv_mfma_kernel<16, 0><<<512, 512, 0, stream>>>(pkbase + pkoff[4], emb,
                                                     whi + 3 * WFP, wlo + 3 * WFP,
                                                     phb + 3 * CH, frest, frest, nullptr);

    // si=5 (pn=32, sel=3): VS 2->4 (2048 blocks = 8/CU; was grid-limited)
    argmin5_fused<<<dim3(512, 4), 256, 0, stream>>>(frest, ehi, elo, nesqh,
                                                    pkbase + pkoff[5]);

    bincount_kernel<<<(NROWS_TOTAL + 255) / 256, 256, 0, stream>>>(pkbase, hits, NROWS_TOTAL);
    finalize_kernel<<<1, 256, 0, stream>>>(hits, laccp, out + (out_size - 2));
}

// Round 13
// 205.471 us; speedup vs baseline: 1.0323x; 1.0323x over previous
//
#include <hip/hip_runtime.h>
#include <math.h>
#include <float.h>

// Problem constants (B=32, C=32, H=W=32, V=4096)
#define BS    32
#define CH    32
#define HH    32
#define VV    4096
#define FELEMS (BS*CH*HH*HH)   // 1048576
#define NROWS_TOTAL 43680      // sum over scales of B*pn*pn
#define BC_BLOCKS ((NROWS_TOTAL + 255) / 256)   // 171

typedef unsigned short ushort_t;
typedef unsigned long long u64_t;
typedef _Float16 half_t;
typedef __attribute__((ext_vector_type(8))) _Float16 half8;
typedef __attribute__((ext_vector_type(4))) float floatx4;

// 2-way fp16 split: x ~= h + l, residual <= 2^-22 |x|
__device__ inline void split2(float x, half_t* h, half_t* l) {
    half_t hh = (half_t)x;
    float r = x - (float)hh;
    *h = hh;
    *l = (half_t)r;
}

// fp32 -> sortable-descending key32 (bigger score => smaller key)
__device__ inline unsigned score_key32(float s) {
    unsigned u = __builtin_bit_cast(unsigned, s);
    unsigned m = (u & 0x80000000u) ? ~u : (u | 0x80000000u);  // monotone asc
    return ~m;                                                 // desc
}

// ---------------------------------------------------------------------------
// prep (grid 1024x256): emb fp16-split + nesqh, zero f_hat output + hits +
// zp pool-accumulators + done-counter, init pk keys to +inf, split conv
// weights into MFMA-A-fragment-ordered global buffers, AND pool si=0 with
// per-block sumsq partials.
__global__ __launch_bounds__(256) void prep_kernel(const float* __restrict__ f,
                                                   const float* __restrict__ emb,
                                                   const float* __restrict__ phw,
                                                   half_t* __restrict__ whi,
                                                   half_t* __restrict__ wlo,
                                                   half_t* __restrict__ ehi,
                                                   half_t* __restrict__ elo,
                                                   float* __restrict__ nesqh,
                                                   float* __restrict__ hits,
                                                   float* __restrict__ laccp,
                                                   unsigned* __restrict__ dcnt,
                                                   half_t* __restrict__ zhi,
                                                   half_t* __restrict__ zlo,
                                                   u64_t* __restrict__ pk,
                                                   float* __restrict__ zpbase,
                                                   float* __restrict__ dout) {
    int gid = blockIdx.x * 256 + threadIdx.x;      // 262144 threads
    float4 z4 = {0.f, 0.f, 0.f, 0.f};
    *(float4*)(dout + (size_t)gid * 4) = z4;
    if (gid < VV) hits[gid] = 0.f;
    if (gid < 8) dcnt[gid] = 0u;
    if (gid < NROWS_TOTAL) pk[gid] = ~0ull;        // +inf keys
    for (int j = gid; j < 348160; j += 262144) zpbase[j] = 0.f;  // pool accum
    if (gid < 36864) {
        // W split-frag pack: idx = ((((phi*2+mt)*9+tau)*4+q)*16+c)*8+k
        int k = gid & 7, c = (gid >> 3) & 15, q = (gid >> 7) & 3;
        int t2 = gid >> 9;                 // 0..71
        int tau = t2 % 9, m2 = t2 / 9;
        int mt = m2 & 1, phi = m2 >> 1;
        int co = mt * 16 + c, ci = q * 8 + k;
        float w = phw[((size_t)(phi * 32 + co) * 32 + ci) * 9 + tau];
        half_t h, l; split2(w, &h, &l);
        whi[gid] = h; wlo[gid] = l;
    }
    if (gid < VV) {
        int v = gid;
        const float* ep = emb + (size_t)v * CH;
        float s = 0.f;
        half_t h[CH], l[CH];
#pragma unroll
        for (int i = 0; i < CH; i++) {
            float e = ep[i];
            s = fmaf(e, e, s);
            split2(e, &h[i], &l[i]);
        }
        nesqh[v] = -0.5f * s;
#pragma unroll
        for (int q = 0; q < 4; q++) {
            half8 H, L;
#pragma unroll
            for (int k = 0; k < 8; k++) {
                H[k] = h[q * 8 + k];
                L[k] = l[q * 8 + k];
            }
            *(half8*)(ehi + (size_t)v * CH + q * 8) = H;
            *(half8*)(elo + (size_t)v * CH + q * 8) = L;
        }
    }

    // pool si=0: pair = blockIdx.x = b*32 + c; base = f + pair*1024
    const int pair = blockIdx.x;
    const float* base = f + (size_t)pair * 1024;
    float s = 0.f, s2 = 0.f;
    for (int p = threadIdx.x; p < 1024; p += 256) {
        float v = base[p];
        s += v;
        s2 = fmaf(v, v, s2);
    }
    __shared__ float sh[256], sh2[256];
    sh[threadIdx.x] = s;
    sh2[threadIdx.x] = s2;
    __syncthreads();
    for (int o = 128; o > 0; o >>= 1) {
        if (threadIdx.x < o) {
            sh[threadIdx.x]  += sh[threadIdx.x + o];
            sh2[threadIdx.x] += sh2[threadIdx.x + o];
        }
        __syncthreads();
    }
    if (threadIdx.x == 0) {
        split2(sh[0] * (1.0f / 1024.0f), &zhi[pair], &zlo[pair]);
        laccp[pair] = sh2[0];      // deterministic partial, summed in finalize
    }
}

// ---------------------------------------------------------------------------
// 3-MFMA fp16 score chain for one 16-row group vs one 16-code tile
// score = z.e - 0.5|e|^2 = ah.bh + ah.bl + al.bh  (al.bl <= 2^-22 dropped)
__device__ inline floatx4 score_chain(half8 ah, half8 al,
                                      half8 bh, half8 bl, floatx4 ehv) {
    floatx4 acc;
    acc = __builtin_amdgcn_mfma_f32_16x16x32_f16(ah, bh, ehv, 0, 0, 0);
    acc = __builtin_amdgcn_mfma_f32_16x16x32_f16(ah, bl, acc, 0, 0, 0);
    acc = __builtin_amdgcn_mfma_f32_16x16x32_f16(al, bh, acc, 0, 0, 0);
    return acc;
}

__device__ inline void sel4(const floatx4& acc, int v, float* best, int* bidx) {
#pragma unroll
    for (int r = 0; r < 4; r++) {
        // strict >: lane-local scan is increasing v -> keeps lowest v on tie
        if (acc[r] > best[r]) { best[r] = acc[r]; bidx[r] = v; }
    }
}

// argmin core — EXACT r7/r9/r10-proven form (measured 200.7us twice).
// r11's peel+VS-doubling REGRESSED (+12us: halved TPW doubled e-re-reads and
// atomic traffic; peel raised VGPR); r8's row-split also regressed. FROZEN.
// 4 waves share rows, scan disjoint t-ranges; 1-deep clamped prefetch;
// deferred-select interleave (RT>=2); cross-block merge via packed-key
// atomicMin (max score, lowest idx on tie == jnp.argmin).
template <int RT, int TPW>
__device__ inline void argmin_body(const half8* a1, const half8* a2,
                                   const half_t* __restrict__ ehi,
                                   const half_t* __restrict__ elo,
                                   const float* __restrict__ nesqh,
                                   u64_t* __restrict__ pk, int row0, int t0) {
    const int tid  = threadIdx.x;
    const int wv   = tid >> 6;
    const int lane = tid & 63;
    const int col  = lane & 15;
    const int quad = lane >> 4;

    float best[RT][4];
    int   bidx[RT][4];
#pragma unroll
    for (int rt = 0; rt < RT; rt++)
#pragma unroll
        for (int r = 0; r < 4; r++) { best[rt][r] = -FLT_MAX; bidx[rt][r] = 0; }

    int t = t0 + wv * TPW;
    const int tend = t + TPW;

    // prefetch tile t
    size_t eoff = ((size_t)((t << 4) + col) << 5) + (quad << 3);
    half8 nb1 = *(const half8*)(ehi + eoff);
    half8 nb2 = *(const half8*)(elo + eoff);
    float neh = nesqh[(t << 4) + col];

    floatx4 acc[RT];
    int vprev = 0;
    if (RT > 1) acc[RT - 1] = floatx4{-FLT_MAX, -FLT_MAX, -FLT_MAX, -FLT_MAX};

    for (; t < tend; t++) {
        const half8 b1 = nb1, b2 = nb2;
        const floatx4 ehv = {neh, neh, neh, neh};
        const int vcur = (t << 4) + col;
        // prefetch t+1 (clamped) before consuming current
        const int tn = (t + 1 < tend) ? (t + 1) : t;
        const size_t eoff2 = ((size_t)((tn << 4) + col) << 5) + (quad << 3);
        nb1 = *(const half8*)(ehi + eoff2);
        nb2 = *(const half8*)(elo + eoff2);
        neh = nesqh[(tn << 4) + col];

        if (RT == 1) {
            acc[0] = score_chain(a1[0], a2[0], b1, b2, ehv);
            sel4(acc[0], vcur, best[0], bidx[0]);
        } else {
            acc[0] = score_chain(a1[0], a2[0], b1, b2, ehv);
            sel4(acc[RT - 1], vprev, best[RT - 1], bidx[RT - 1]);  // deferred
#pragma unroll
            for (int rt = 1; rt < RT; rt++) {
                acc[rt] = score_chain(a1[rt], a2[rt], b1, b2, ehv);
                sel4(acc[rt - 1], vcur, best[rt - 1], bidx[rt - 1]);
            }
            vprev = vcur;
        }
    }
    if (RT > 1) sel4(acc[RT - 1], vprev, best[RT - 1], bidx[RT - 1]);

    // reduce across the 16 cols (v within tile) of each quad group
#pragma unroll
    for (int m = 1; m < 16; m <<= 1) {
#pragma unroll
        for (int rt = 0; rt < RT; rt++)
#pragma unroll
            for (int r = 0; r < 4; r++) {
                float s2 = __shfl_xor(best[rt][r], m, 64);
                int   v2 = __shfl_xor(bidx[rt][r], m, 64);
                if (s2 > best[rt][r] ||
                    (s2 == best[rt][r] && v2 < bidx[rt][r])) {
                    best[rt][r] = s2; bidx[rt][r] = v2;
                }
            }
    }

    __shared__ float sbs[4 * RT * 16];
    __shared__ int   sbi[4 * RT * 16];
    if (col == 0) {
#pragma unroll
        for (int rt = 0; rt < RT; rt++)
#pragma unroll
            for (int r = 0; r < 4; r++) {
                int row = rt * 16 + (quad << 2) + r;
                sbs[wv * RT * 16 + row] = best[rt][r];
                sbi[wv * RT * 16 + row] = bidx[rt][r];
            }
    }
    __syncthreads();
    if (tid < RT * 16) {
        float s = sbs[tid];
        int   v = sbi[tid];
        for (int w = 1; w < 4; w++) {
            float s2 = sbs[w * RT * 16 + tid];
            int   v2 = sbi[w * RT * 16 + tid];
            if (s2 > s || (s2 == s && v2 < v)) { s = s2; v = v2; }
        }
        u64_t key = ((u64_t)score_key32(s) << 32) | (unsigned)v;
        atomicMin(pk + row0 + tid, key);
    }
}

// generic stage: z-splits from memory (si=0 only). grid = (nRowBlocks, VS)
template <int RT, int VS>
__global__ __launch_bounds__(256) void argmin_stage(const half_t* __restrict__ zhi,
                                                    const half_t* __restrict__ zlo,
                                                    const half_t* __restrict__ ehi,
                                                    const half_t* __restrict__ elo,
                                                    const float* __restrict__ nesqh,
                                                    u64_t* __restrict__ pk) {
    const int lane = threadIdx.x & 63;
    const int col  = lane & 15;
    const int quad = lane >> 4;
    const int row0 = blockIdx.x * (16 * RT);

    half8 a1[RT], a2[RT];
#pragma unroll
    for (int rt = 0; rt < RT; rt++) {
        size_t off = ((size_t)(row0 + rt * 16 + col) << 5) + (quad << 3);
        a1[rt] = *(const half8*)(zhi + off);
        a2[rt] = *(const half8*)(zlo + off);
    }
    argmin_body<RT, 64 / VS>(a1, a2, ehi, elo, nesqh, pk,
                             row0, (int)blockIdx.y * (256 / VS));
}

// zp stage (si=1..4): pooled z arrives fully accumulated (conv epilogue
// atomicAdds into a zeroed per-scale slice). Scale by exact pow2 1/ps'^2,
// split2 in-register.
template <int RT, int VS, int PN>
__global__ __launch_bounds__(256) void argmin_zp(const float* __restrict__ zp,
                                                 const half_t* __restrict__ ehi,
                                                 const half_t* __restrict__ elo,
                                                 const float* __restrict__ nesqh,
                                                 u64_t* __restrict__ pk) {
    const int lane = threadIdx.x & 63;
    const int col  = lane & 15;
    const int quad = lane >> 4;
    const int row0 = blockIdx.x * (16 * RT);
    constexpr int PSP = 32 / PN;
    const float scale = 1.0f / (float)(PSP * PSP);

    half8 a1[RT], a2[RT];
#pragma unroll
    for (int rt = 0; rt < RT; rt++) {
        const float* p = zp + (size_t)(row0 + rt * 16 + col) * CH + (quad << 3);
        float4 v0 = *(const float4*)p;
        float4 v1 = *(const float4*)(p + 4);
        float s[8] = {v0.x, v0.y, v0.z, v0.w, v1.x, v1.y, v1.z, v1.w};
#pragma unroll
        for (int k = 0; k < 8; k++) {
            half_t h, l;
            split2(s[k] * scale, &h, &l);
            a1[rt][k] = h; a2[rt][k] = l;
        }
    }
    argmin_body<RT, 64 / VS>(a1, a2, ehi, elo, nesqh, pk,
                             row0, (int)blockIdx.y * (256 / VS));
}

// si=5 fused: pool is identity (pn=32) -> split2 straight from frest.
// grid = (512, 2): RT=4, VS=2, each wave scans 32 tiles (r7-proven config;
// r11's (512,4) regressed).
__global__ __launch_bounds__(256) void argmin5_fused(const float* __restrict__ frest,
                                                     const half_t* __restrict__ ehi,
                                                     const half_t* __restrict__ elo,
                                                     const float* __restrict__ nesqh,
                                                     u64_t* __restrict__ pk) {
    const int lane = threadIdx.x & 63;
    const int col  = lane & 15;
    const int quad = lane >> 4;
    const int row0 = blockIdx.x * 64;   // RT=4

    half8 a1[4], a2[4];
#pragma unroll
    for (int rt = 0; rt < 4; rt++) {
        int n = row0 + rt * 16 + col;               // row = (b*32+i)*32+j
        int b = n >> 10, i = (n >> 5) & 31, j = n & 31;
        const float* p = frest + ((((size_t)(b * CH + quad * 8)) * HH + i) * HH + j);
#pragma unroll
        for (int k = 0; k < 8; k++) {
            half_t h, l;
            split2(p[(size_t)k * (HH * HH)], &h, &l);   // c stride = 1024
            a1[rt][k] = h; a2[rt][k] = l;
        }
    }
    argmin_body<4, 32>(a1, a2, ehi, elo, nesqh, pk,
                       row0, (int)blockIdx.y * 128);
}

// ---------------------------------------------------------------------------
// bicubic weights, a=-0.75, half-pixel, edge clamp (matches ref _bicubic_mat)
__device__ inline void cubic_w(float xs, int pn, int* ix, float* w) {
    const float a = -0.75f;
    float xf = floorf(xs);
    int x0 = (int)xf;
    float t = xs - xf;
#pragma unroll
    for (int j = -1; j <= 2; j++) {
        float d = fabsf(t - (float)j);
        float ww;
        if (d < 1.0f)      ww = ((a + 2.0f) * d - (a + 3.0f)) * d * d + 1.0f;
        else if (d < 2.0f) ww = ((a * d - 5.0f * a) * d + 8.0f * a) * d - 4.0f * a;
        else               ww = 0.0f;
        int xi = x0 + j;
        xi = xi < 0 ? 0 : (xi > pn - 1 ? pn - 1 : xi);
        ix[j + 1] = xi;
        w[j + 1]  = ww;
    }
}

// ---------------------------------------------------------------------------
// MFMA conv: dst = src - (0.5*h + 0.5*(conv3x3(h)+bias)), h = bicubic
// upsample, fp16-split into LDS, consumed by 16x16x32 f16 MFMA 3-chains
// (r7-verified fragment convention; r9 LDS window tables; r10 512x512 shape).
template <int PN, int PN_NEXT>
__global__ __launch_bounds__(512) void conv_mfma_kernel(const u64_t* __restrict__ pk,
                                                        const float* __restrict__ emb,
                                                        const half_t* __restrict__ whi,
                                                        const half_t* __restrict__ wlo,
                                                        const float* __restrict__ bias,
                                                        const float* __restrict__ src,
                                                        float* __restrict__ dst,
                                                        float* __restrict__ zp) {
    constexpr int IYB = (PN <= 4) ? PN : 6;   // iy tap band (span<=5 here)
    const int t    = threadIdx.x;
    const int lane = t & 63, col = lane & 15, quad = lane >> 4;
    const int wid  = t >> 6;                  // 0..7
    const int Nt   = wid >> 1, mt = wid & 1;
    const int ty   = Nt >> 1, xh = Nt & 1;    // ty 0..1
    const int yt   = blockIdx.x & 15, b = blockIdx.x >> 4;
    const int y0   = yt * 2;

    __shared__ half8 Hhi8[544], Hlo8[544];    // 4*34*32 halves = 8704 B each
    __shared__ float cache[IYB][PN][32];      // emb rows, ch-minor
    __shared__ int   riy[4][4];               // iy - iy_lo per staged row
    __shared__ float rwy[4][4];
    __shared__ int   cxs[34][4];              // col windows (gx = cl-1)
    __shared__ float cws[34][4];
    half_t* Hhi = (half_t*)Hhi8;
    half_t* Hlo = (half_t*)Hlo8;

    const float scale = (float)PN / (float)HH;
    int iy_lo = 0;
    if (PN > 4) {
        int lo = (int)floorf(((float)(y0 - 1) + 0.5f) * scale - 0.5f) - 1;
        lo = lo < 0 ? 0 : lo;
        lo = lo > PN - IYB ? PN - IYB : lo;
        iy_lo = lo;
    }

    // emb gather -> cache (float4 per 4ch; winner idx straight from pk, L2)
    const u64_t* pkb = pk + b * PN * PN;
    for (int i = t; i < IYB * PN * 8; i += 512) {
        int chg = i & 7, cell = i >> 3;
        int ix = cell % PN, iyb = cell / PN;
        int idx = (int)(unsigned)(pkb[(iy_lo + iyb) * PN + ix] & 0xFFFFFFFFull);
        *(float4*)&cache[iyb][ix][chg * 4] =
            *(const float4*)(emb + (size_t)idx * CH + chg * 4);
    }
    // bicubic window tables (disjoint thread ranges, concurrent with gather)
    if (t < 4) {
        int iy[4]; float wy[4];
        cubic_w(((float)(y0 - 1 + t) + 0.5f) * scale - 0.5f, PN, iy, wy);
#pragma unroll
        for (int a = 0; a < 4; a++) { riy[t][a] = iy[a] - iy_lo; rwy[t][a] = wy[a]; }
    }
    if (t >= 64 && t < 98) {
        int cl = t - 64;                  // col 0..33, gx = cl-1
        int ix[4]; float wx[4];
        cubic_w(((float)(cl - 1) + 0.5f) * scale - 0.5f, PN, ix, wx);
#pragma unroll
        for (int a = 0; a < 4; a++) { cxs[cl][a] = ix[a]; cws[cl][a] = wx[a]; }
    }
    __syncthreads();

    // bicubic staging -> H fp16-split (4 ch per iter; windows from LDS,
    // values & fma order bit-identical). 136 cells (4 rows x 34 cols) x 8.
    for (int i = t; i < 1088; i += 512) {
        int chg = i & 7, cell = i >> 3;
        int xs = cell % 34, row = cell / 34;     // row 0..3
        int gy = y0 - 1 + row, gx = xs - 1;
        float s0 = 0.f, s1 = 0.f, s2 = 0.f, s3 = 0.f;
        if ((unsigned)gy < 32u && (unsigned)gx < 32u) {
#pragma unroll
            for (int a = 0; a < 4; a++) {
                const int iyb = riy[row][a];
                const float wya = rwy[row][a];
                float r0 = 0.f, r1 = 0.f, r2 = 0.f, r3 = 0.f;
#pragma unroll
                for (int b2 = 0; b2 < 4; b2++) {
                    const float4 tv = *(const float4*)&cache[iyb][cxs[xs][b2]][chg * 4];
                    const float wxb = cws[xs][b2];
                    r0 = fmaf(tv.x, wxb, r0);
                    r1 = fmaf(tv.y, wxb, r1);
                    r2 = fmaf(tv.z, wxb, r2);
                    r3 = fmaf(tv.w, wxb, r3);
                }
                s0 = fmaf(r0, wya, s0);
                s1 = fmaf(r1, wya, s1);
                s2 = fmaf(r2, wya, s2);
                s3 = fmaf(r3, wya, s3);
            }
        }
        const int ho = cell * 32 + chg * 4;
        half_t h, l;
        split2(s0, &h, &l); Hhi[ho + 0] = h; Hlo[ho + 0] = l;
        split2(s1, &h, &l); Hhi[ho + 1] = h; Hlo[ho + 1] = l;
        split2(s2, &h, &l); Hhi[ho + 2] = h; Hlo[ho + 2] = l;
        split2(s3, &h, &l); Hhi[ho + 3] = h; Hlo[ho + 3] = l;
    }
    __syncthreads();

    // 9-tap MFMA accumulation; C-init = bias per output row (co)
    const float4 bv = *(const float4*)(bias + mt * 16 + quad * 4);
    floatx4 acc = {bv.x, bv.y, bv.z, bv.w};
#pragma unroll
    for (int tau = 0; tau < 9; tau++) {
        const int dy = tau / 3, dx = tau % 3;
        const int woff = (mt * 9 + tau) * 512 + quad * 128 + col * 8;
        const half8 wh = *(const half8*)(whi + woff);
        const half8 wl = *(const half8*)(wlo + woff);
        const int hoff = ((ty + dy) * 34 + xh * 16 + dx + col) * 32 + quad * 8;
        const half8 hh = *(const half8*)(Hhi + hoff);
        const half8 hl = *(const half8*)(Hlo + hoff);
        acc = __builtin_amdgcn_mfma_f32_16x16x32_f16(wh, hh, acc, 0, 0, 0);
        acc = __builtin_amdgcn_mfma_f32_16x16x32_f16(wh, hl, acc, 0, 0, 0);
        acc = __builtin_amdgcn_mfma_f32_16x16x32_f16(wl, hh, acc, 0, 0, 0);
    }

    // epilogue: residual + store; lane owns pix (y0+ty, xh*16+col), 4 co's
    const int x = xh * 16 + col, y = y0 + ty;
    const int hcell = ((ty + 1) * 34 + (x + 1)) * 32;
    float pv[4];
#pragma unroll
    for (int r = 0; r < 4; r++) {
        const int c = mt * 16 + quad * 4 + r;
        const float hc = (float)Hhi[hcell + c] + (float)Hlo[hcell + c];
        const size_t off = (((size_t)(b * CH + c)) * HH + y) * HH + x;
        const float dv = src[off] - (0.5f * hc + 0.5f * acc[r]);
        dst[off] = dv;
        pv[r] = dv;
    }

    if constexpr (PN_NEXT != 0) {
        constexpr int PSP = 32 / PN_NEXT;        // 16/8/4/2 (<=16: in-wave x)
#pragma unroll
        for (int m = 1; m < PSP; m <<= 1)        // col bits only, stays in quad
#pragma unroll
            for (int r = 0; r < 4; r++) pv[r] += __shfl_xor(pv[r], m, 64);
        if ((col & (PSP - 1)) == 0) {
            const int wx = x / PSP, wy = y / PSP;
#pragma unroll
            for (int r = 0; r < 4; r++) {
                const int c = mt * 16 + quad * 4 + r;
                atomicAdd(zp + ((size_t)((b * PN_NEXT + wy) * PN_NEXT + wx)) * CH + c,
                          pv[r]);
            }
        }
    }
}

// ---------------------------------------------------------------------------
// bincount + finalize in ONE kernel (last-block-done pattern, r13): 171
// blocks bincount via device-scope atomics; release fence + done-counter;
// the last block alone computes perplexity + loss. Saves one serial launch
// boundary (r3 lesson: single-block bincount was 60us; this keeps bincount
// parallel and only the 3us finalize serial).
__global__ __launch_bounds__(256) void bincount_finalize_kernel(
        const u64_t* __restrict__ pk, float* __restrict__ hits,
        const float* __restrict__ laccp, unsigned* __restrict__ dcnt,
        float* __restrict__ outs, int n, int nblocks) {
    int i = blockIdx.x * 256 + threadIdx.x;
    if (i < n) {
        int idx = (int)(unsigned)(pk[i] & 0xFFFFFFFFull);
        atomicAdd(&hits[idx], 1.0f);
    }
    __threadfence();                       // release: hits visible device-wide
    __shared__ unsigned slast;
    if (threadIdx.x == 0) slast = atomicAdd(dcnt, 1u);
    __syncthreads();
    if (slast != (unsigned)(nblocks - 1)) return;
    __threadfence();                       // acquire: see all blocks' hits

    __shared__ float sh[256];
    int t = threadIdx.x;
    const float tot = (float)NROWS_TOTAL;  // each row contributes one hit
    float ent = 0.f;
    for (int v = t; v < VV; v += 256) {
        float p = hits[v] / tot;
        ent += p * logf(p + 1e-10f);
    }
    sh[t] = ent;
    __syncthreads();
    for (int o = 128; o > 0; o >>= 1) {
        if (t < o) sh[t] += sh[t + o];
        __syncthreads();
    }
    float entT = sh[0];
    __syncthreads();
    float ls = 0.f;
    for (int i2 = t; i2 < 1024; i2 += 256) ls += laccp[i2];
    sh[t] = ls;
    __syncthreads();
    for (int o = 128; o > 0; o >>= 1) {
        if (t < o) sh[t] += sh[t + o];
        __syncthreads();
    }
    if (t == 0) {
        // loss = SN*(1+BETA)*mean(f^2) = 7.5 * sumsq / 1048576  (f_hat stays 0)
        outs[0] = 7.5f * sh[0] * (1.0f / (float)FELEMS);
        outs[1] = expf(-entT);
    }
}

// ---------------------------------------------------------------------------
extern "C" void kernel_launch(void* const* d_in, const int* in_sizes, int n_in,
                              void* d_out, int out_size, void* d_ws, size_t ws_size,
                              hipStream_t stream) {
    const float* f   = (const float*)d_in[0];   // (32,32,32,32)
    const float* emb = (const float*)d_in[1];   // (4096,32)
    const float* phw = (const float*)d_in[2];   // (4,32,32,3,3)
    const float* phb = (const float*)d_in[3];   // (4,32)
    float* out = (float*)d_out;                 // f_hat (1048576) + loss + perplexity

    float* ws      = (float*)d_ws;
    float* hits    = ws;                              // [0, 4096)
    float* laccp   = ws + 4096;                       // [4096, 5120) partials
    unsigned* dcnt = (unsigned*)(ws + 5120);          // [5120, 5128) done ctr
    u64_t* pkbase  = (u64_t*)(ws + 8448);             // 43680 u64 -> [8448, 95808)
    float* frest   = ws + 95808;                      // [95808, 1144384)
    half_t* zhi    = (half_t*)(ws + 1144384);         // si=0 z-split (1024 used)
    half_t* zlo    = (half_t*)(ws + 1275456);
    float* nesqh   = ws + 1537600;                    // [1537600, 1541696)
    half_t* ehi    = (half_t*)(ws + 2590272);         // 131072 halves
    half_t* elo    = (half_t*)(ws + 2655808);         // ends 2721344
    float* zp      = ws + 2721344;                    // 348160 f -> ends 3069504
    half_t* whi    = (half_t*)(ws + 3069504);         // 36864 halves
    half_t* wlo    = (half_t*)(ws + 3087936);         // ends 3106368 (12.4 MB)

    // zp slices (zeroed once in prep; each written by exactly one conv)
    float* zp1 = zp;            // PN_NEXT=2:  4096
    float* zp2 = zp + 4096;     // PN_NEXT=4:  16384
    float* zp3 = zp + 20480;    // PN_NEXT=8:  65536
    float* zp4 = zp + 86016;    // PN_NEXT=16: 262144 -> total 348160

    prep_kernel<<<1024, 256, 0, stream>>>(f, emb, phw, whi, wlo, ehi, elo, nesqh,
                                          hits, laccp, dcnt, zhi, zlo, pkbase,
                                          zp, out);

    const int pkoff[6] = {0, 32, 160, 672, 2720, 10912};
    const size_t WFP = 9216;                          // halves per phi frag-pack

    // si=0 (pn=1, sel=0)
    argmin_stage<1, 16><<<dim3(2, 16), 256, 0, stream>>>(zhi, zlo, ehi, elo, nesqh,
                                                         pkbase + pkoff[0]);
    conv_mfma_kernel<1, 2><<<512, 512, 0, stream>>>(pkbase + pkoff[0], emb,
                                                    whi + 0 * WFP, wlo + 0 * WFP,
                                                    phb + 0 * CH, f, frest, zp1);

    // si=1 (pn=2, sel=0)
    argmin_zp<1, 16, 2><<<dim3(8, 16), 256, 0, stream>>>(zp1, ehi, elo, nesqh,
                                                         pkbase + pkoff[1]);
    conv_mfma_kernel<2, 4><<<512, 512, 0, stream>>>(pkbase + pkoff[1], emb,
                                                    whi + 0 * WFP, wlo + 0 * WFP,
                                                    phb + 0 * CH, frest, frest, zp2);

    // si=2 (pn=4, sel=1)
    argmin_zp<1, 16, 4><<<dim3(32, 16), 256, 0, stream>>>(zp2, ehi, elo, nesqh,
                                                          pkbase + pkoff[2]);
    conv_mfma_kernel<4, 8><<<512, 512, 0, stream>>>(pkbase + pkoff[2], emb,
                                                    whi + 1 * WFP, wlo + 1 * WFP,
                                                    phb + 1 * CH, frest, frest, zp3);

    // si=3 (pn=8, sel=2)
    argmin_zp<1, 8, 8><<<dim3(128, 8), 256, 0, stream>>>(zp3, ehi, elo, nesqh,
                                                         pkbase + pkoff[3]);
    conv_mfma_kernel<8, 16><<<512, 512, 0, stream>>>(pkbase + pkoff[3], emb,
                                                     whi + 2 * WFP, wlo + 2 * WFP,
                                                     phb + 2 * CH, frest, frest, zp4);

    // si=4 (pn=16, sel=3): r7-proven config (grid (256,4), RT=2)
    argmin_zp<2, 4, 16><<<dim3(256, 4), 256, 0, stream>>>(zp4, ehi, elo, nesqh,
                                                          pkbase + pkoff[4]);
    conv_mfma_kernel<16, 0><<<512, 512, 0, stream>>>(pkbase + pkoff[4], emb,
                                                     whi + 3 * WFP, wlo + 3 * WFP,
                                                     phb + 3 * CH, frest, frest, nullptr);

    // si=5 (pn=32, sel=3): fused identity-pool argmin (r7-proven (512,2))
    argmin5_fused<<<dim3(512, 2), 256, 0, stream>>>(frest, ehi, elo, nesqh,
                                                    pkbase + pkoff[5]);

    bincount_finalize_kernel<<<BC_BLOCKS, 256, 0, stream>>>(
        pkbase, hits, laccp, dcnt, out + (out_size - 2), NROWS_TOTAL, BC_BLOCKS);
}

// Round 14
// 200.029 us; speedup vs baseline: 1.0604x; 1.0272x over previous
//
#include <hip/hip_runtime.h>
#include <math.h>
#include <float.h>

// Problem constants (B=32, C=32, H=W=32, V=4096)
#define BS    32
#define CH    32
#define HH    32
#define VV    4096
#define FELEMS (BS*CH*HH*HH)   // 1048576
#define NROWS_TOTAL 43680      // sum over scales of B*pn*pn

typedef unsigned short ushort_t;
typedef unsigned long long u64_t;
typedef _Float16 half_t;
typedef __attribute__((ext_vector_type(8))) _Float16 half8;
typedef __attribute__((ext_vector_type(4))) float floatx4;

// 2-way fp16 split: x ~= h + l, residual <= 2^-22 |x|
__device__ inline void split2(float x, half_t* h, half_t* l) {
    half_t hh = (half_t)x;
    float r = x - (float)hh;
    *h = hh;
    *l = (half_t)r;
}

// fp32 -> sortable-descending key32 (bigger score => smaller key)
__device__ inline unsigned score_key32(float s) {
    unsigned u = __builtin_bit_cast(unsigned, s);
    unsigned m = (u & 0x80000000u) ? ~u : (u | 0x80000000u);  // monotone asc
    return ~m;                                                 // desc
}

// ---------------------------------------------------------------------------
// prep (grid 1024x256): emb fp16-split + nesqh, zero f_hat output + hits +
// zp pool-accumulators, init pk keys to +inf, split conv weights into
// MFMA-A-fragment-ordered global buffers (lane col=co, 8 ci per quad),
// AND pool si=0 with per-block sumsq partials.
__global__ __launch_bounds__(256) void prep_kernel(const float* __restrict__ f,
                                                   const float* __restrict__ emb,
                                                   const float* __restrict__ phw,
                                                   half_t* __restrict__ whi,
                                                   half_t* __restrict__ wlo,
                                                   half_t* __restrict__ ehi,
                                                   half_t* __restrict__ elo,
                                                   float* __restrict__ nesqh,
                                                   float* __restrict__ hits,
                                                   float* __restrict__ laccp,
                                                   half_t* __restrict__ zhi,
                                                   half_t* __restrict__ zlo,
                                                   u64_t* __restrict__ pk,
                                                   float* __restrict__ zpbase,
                                                   float* __restrict__ dout) {
    int gid = blockIdx.x * 256 + threadIdx.x;      // 262144 threads
    float4 z4 = {0.f, 0.f, 0.f, 0.f};
    *(float4*)(dout + (size_t)gid * 4) = z4;
    if (gid < VV) hits[gid] = 0.f;
    if (gid < NROWS_TOTAL) pk[gid] = ~0ull;        // +inf keys
    for (int j = gid; j < 348160; j += 262144) zpbase[j] = 0.f;  // pool accum
    if (gid < 36864) {
        // W split-frag pack: idx = ((((phi*2+mt)*9+tau)*4+q)*16+c)*8+k
        int k = gid & 7, c = (gid >> 3) & 15, q = (gid >> 7) & 3;
        int t2 = gid >> 9;                 // 0..71
        int tau = t2 % 9, m2 = t2 / 9;
        int mt = m2 & 1, phi = m2 >> 1;
        int co = mt * 16 + c, ci = q * 8 + k;
        float w = phw[((size_t)(phi * 32 + co) * 32 + ci) * 9 + tau];
        half_t h, l; split2(w, &h, &l);
        whi[gid] = h; wlo[gid] = l;
    }
    if (gid < VV) {
        int v = gid;
        const float* ep = emb + (size_t)v * CH;
        float s = 0.f;
        half_t h[CH], l[CH];
#pragma unroll
        for (int i = 0; i < CH; i++) {
            float e = ep[i];
            s = fmaf(e, e, s);
            split2(e, &h[i], &l[i]);
        }
        nesqh[v] = -0.5f * s;
#pragma unroll
        for (int q = 0; q < 4; q++) {
            half8 H, L;
#pragma unroll
            for (int k = 0; k < 8; k++) {
                H[k] = h[q * 8 + k];
                L[k] = l[q * 8 + k];
            }
            *(half8*)(ehi + (size_t)v * CH + q * 8) = H;
            *(half8*)(elo + (size_t)v * CH + q * 8) = L;
        }
    }

    // pool si=0: pair = blockIdx.x = b*32 + c; base = f + pair*1024
    const int pair = blockIdx.x;
    const float* base = f + (size_t)pair * 1024;
    float s = 0.f, s2 = 0.f;
    for (int p = threadIdx.x; p < 1024; p += 256) {
        float v = base[p];
        s += v;
        s2 = fmaf(v, v, s2);
    }
    __shared__ float sh[256], sh2[256];
    sh[threadIdx.x] = s;
    sh2[threadIdx.x] = s2;
    __syncthreads();
    for (int o = 128; o > 0; o >>= 1) {
        if (threadIdx.x < o) {
            sh[threadIdx.x]  += sh[threadIdx.x + o];
            sh2[threadIdx.x] += sh2[threadIdx.x + o];
        }
        __syncthreads();
    }
    if (threadIdx.x == 0) {
        split2(sh[0] * (1.0f / 1024.0f), &zhi[pair], &zlo[pair]);
        laccp[pair] = sh2[0];      // deterministic partial, summed in finalize
    }
}

// ---------------------------------------------------------------------------
// 3-MFMA fp16 score chain for one 16-row group vs one 16-code tile
// score = z.e - 0.5|e|^2 = ah.bh + ah.bl + al.bh  (al.bl <= 2^-22 dropped)
__device__ inline floatx4 score_chain(half8 ah, half8 al,
                                      half8 bh, half8 bl, floatx4 ehv) {
    floatx4 acc;
    acc = __builtin_amdgcn_mfma_f32_16x16x32_f16(ah, bh, ehv, 0, 0, 0);
    acc = __builtin_amdgcn_mfma_f32_16x16x32_f16(ah, bl, acc, 0, 0, 0);
    acc = __builtin_amdgcn_mfma_f32_16x16x32_f16(al, bh, acc, 0, 0, 0);
    return acc;
}

__device__ inline void sel4(const floatx4& acc, int v, float* best, int* bidx) {
#pragma unroll
    for (int r = 0; r < 4; r++) {
        // strict >: lane-local scan is increasing v -> keeps lowest v on tie
        if (acc[r] > best[r]) { best[r] = acc[r]; bidx[r] = v; }
    }
}

// argmin core — EXACT r7/r9/r10-proven form (measured 200.7us twice; FROZEN
// after 3 failed structural attacks: r8 row-split, r11 peel+VS-double, and
// the prior session's 2-deep/VS-ladder/pooled-stage variants).
// 4 waves share rows, scan disjoint t-ranges; 1-deep clamped prefetch;
// deferred-select interleave (RT>=2); cross-block merge via packed-key
// atomicMin (max score, lowest idx on tie == jnp.argmin).
template <int RT, int TPW>
__device__ inline void argmin_body(const half8* a1, const half8* a2,
                                   const half_t* __restrict__ ehi,
                                   const half_t* __restrict__ elo,
                                   const float* __restrict__ nesqh,
                                   u64_t* __restrict__ pk, int row0, int t0) {
    const int tid  = threadIdx.x;
    const int wv   = tid >> 6;
    const int lane = tid & 63;
    const int col  = lane & 15;
    const int quad = lane >> 4;

    float best[RT][4];
    int   bidx[RT][4];
#pragma unroll
    for (int rt = 0; rt < RT; rt++)
#pragma unroll
        for (int r = 0; r < 4; r++) { best[rt][r] = -FLT_MAX; bidx[rt][r] = 0; }

    int t = t0 + wv * TPW;
    const int tend = t + TPW;

    // prefetch tile t
    size_t eoff = ((size_t)((t << 4) + col) << 5) + (quad << 3);
    half8 nb1 = *(const half8*)(ehi + eoff);
    half8 nb2 = *(const half8*)(elo + eoff);
    float neh = nesqh[(t << 4) + col];

    floatx4 acc[RT];
    int vprev = 0;
    if (RT > 1) acc[RT - 1] = floatx4{-FLT_MAX, -FLT_MAX, -FLT_MAX, -FLT_MAX};

    for (; t < tend; t++) {
        const half8 b1 = nb1, b2 = nb2;
        const floatx4 ehv = {neh, neh, neh, neh};
        const int vcur = (t << 4) + col;
        // prefetch t+1 (clamped) before consuming current
        const int tn = (t + 1 < tend) ? (t + 1) : t;
        const size_t eoff2 = ((size_t)((tn << 4) + col) << 5) + (quad << 3);
        nb1 = *(const half8*)(ehi + eoff2);
        nb2 = *(const half8*)(elo + eoff2);
        neh = nesqh[(tn << 4) + col];

        if (RT == 1) {
            acc[0] = score_chain(a1[0], a2[0], b1, b2, ehv);
            sel4(acc[0], vcur, best[0], bidx[0]);
        } else {
            acc[0] = score_chain(a1[0], a2[0], b1, b2, ehv);
            sel4(acc[RT - 1], vprev, best[RT - 1], bidx[RT - 1]);  // deferred
#pragma unroll
            for (int rt = 1; rt < RT; rt++) {
                acc[rt] = score_chain(a1[rt], a2[rt], b1, b2, ehv);
                sel4(acc[rt - 1], vcur, best[rt - 1], bidx[rt - 1]);
            }
            vprev = vcur;
        }
    }
    if (RT > 1) sel4(acc[RT - 1], vprev, best[RT - 1], bidx[RT - 1]);

    // reduce across the 16 cols (v within tile) of each quad group
#pragma unroll
    for (int m = 1; m < 16; m <<= 1) {
#pragma unroll
        for (int rt = 0; rt < RT; rt++)
#pragma unroll
            for (int r = 0; r < 4; r++) {
                float s2 = __shfl_xor(best[rt][r], m, 64);
                int   v2 = __shfl_xor(bidx[rt][r], m, 64);
                if (s2 > best[rt][r] ||
                    (s2 == best[rt][r] && v2 < bidx[rt][r])) {
                    best[rt][r] = s2; bidx[rt][r] = v2;
                }
            }
    }

    __shared__ float sbs[4 * RT * 16];
    __shared__ int   sbi[4 * RT * 16];
    if (col == 0) {
#pragma unroll
        for (int rt = 0; rt < RT; rt++)
#pragma unroll
            for (int r = 0; r < 4; r++) {
                int row = rt * 16 + (quad << 2) + r;
                sbs[wv * RT * 16 + row] = best[rt][r];
                sbi[wv * RT * 16 + row] = bidx[rt][r];
            }
    }
    __syncthreads();
    if (tid < RT * 16) {
        float s = sbs[tid];
        int   v = sbi[tid];
        for (int w = 1; w < 4; w++) {
            float s2 = sbs[w * RT * 16 + tid];
            int   v2 = sbi[w * RT * 16 + tid];
            if (s2 > s || (s2 == s && v2 < v)) { s = s2; v = v2; }
        }
        u64_t key = ((u64_t)score_key32(s) << 32) | (unsigned)v;
        atomicMin(pk + row0 + tid, key);
    }
}

// generic stage: z-splits from memory (si=0 only). grid = (nRowBlocks, VS)
template <int RT, int VS>
__global__ __launch_bounds__(256) void argmin_stage(const half_t* __restrict__ zhi,
                                                    const half_t* __restrict__ zlo,
                                                    const half_t* __restrict__ ehi,
                                                    const half_t* __restrict__ elo,
                                                    const float* __restrict__ nesqh,
                                                    u64_t* __restrict__ pk) {
    const int lane = threadIdx.x & 63;
    const int col  = lane & 15;
    const int quad = lane >> 4;
    const int row0 = blockIdx.x * (16 * RT);

    half8 a1[RT], a2[RT];
#pragma unroll
    for (int rt = 0; rt < RT; rt++) {
        size_t off = ((size_t)(row0 + rt * 16 + col) << 5) + (quad << 3);
        a1[rt] = *(const half8*)(zhi + off);
        a2[rt] = *(const half8*)(zlo + off);
    }
    argmin_body<RT, 64 / VS>(a1, a2, ehi, elo, nesqh, pk,
                             row0, (int)blockIdx.y * (256 / VS));
}

// zp stage (si=1..4): pooled z arrives fully accumulated (conv epilogue
// atomicAdds into a zeroed per-scale slice). Scale by exact pow2 1/ps'^2,
// split2 in-register.
template <int RT, int VS, int PN>
__global__ __launch_bounds__(256) void argmin_zp(const float* __restrict__ zp,
                                                 const half_t* __restrict__ ehi,
                                                 const half_t* __restrict__ elo,
                                                 const float* __restrict__ nesqh,
                                                 u64_t* __restrict__ pk) {
    const int lane = threadIdx.x & 63;
    const int col  = lane & 15;
    const int quad = lane >> 4;
    const int row0 = blockIdx.x * (16 * RT);
    constexpr int PSP = 32 / PN;
    const float scale = 1.0f / (float)(PSP * PSP);

    half8 a1[RT], a2[RT];
#pragma unroll
    for (int rt = 0; rt < RT; rt++) {
        const float* p = zp + (size_t)(row0 + rt * 16 + col) * CH + (quad << 3);
        float4 v0 = *(const float4*)p;
        float4 v1 = *(const float4*)(p + 4);
        float s[8] = {v0.x, v0.y, v0.z, v0.w, v1.x, v1.y, v1.z, v1.w};
#pragma unroll
        for (int k = 0; k < 8; k++) {
            half_t h, l;
            split2(s[k] * scale, &h, &l);
            a1[rt][k] = h; a2[rt][k] = l;
        }
    }
    argmin_body<RT, 64 / VS>(a1, a2, ehi, elo, nesqh, pk,
                             row0, (int)blockIdx.y * (256 / VS));
}

// si=5 fused: pool is identity (pn=32) -> split2 straight from frest.
// grid = (512, 2): RT=4, VS=2, each wave scans 32 tiles (r7-proven config;
// r11's (512,4) regressed).
__global__ __launch_bounds__(256) void argmin5_fused(const float* __restrict__ frest,
                                                     const half_t* __restrict__ ehi,
                                                     const half_t* __restrict__ elo,
                                                     const float* __restrict__ nesqh,
                                                     u64_t* __restrict__ pk) {
    const int lane = threadIdx.x & 63;
    const int col  = lane & 15;
    const int quad = lane >> 4;
    const int row0 = blockIdx.x * 64;   // RT=4

    half8 a1[4], a2[4];
#pragma unroll
    for (int rt = 0; rt < 4; rt++) {
        int n = row0 + rt * 16 + col;               // row = (b*32+i)*32+j
        int b = n >> 10, i = (n >> 5) & 31, j = n & 31;
        const float* p = frest + ((((size_t)(b * CH + quad * 8)) * HH + i) * HH + j);
#pragma unroll
        for (int k = 0; k < 8; k++) {
            half_t h, l;
            split2(p[(size_t)k * (HH * HH)], &h, &l);   // c stride = 1024
            a1[rt][k] = h; a2[rt][k] = l;
        }
    }
    argmin_body<4, 32>(a1, a2, ehi, elo, nesqh, pk,
                       row0, (int)blockIdx.y * 128);
}

// ---------------------------------------------------------------------------
// bicubic weights, a=-0.75, half-pixel, edge clamp (matches ref _bicubic_mat)
__device__ inline void cubic_w(float xs, int pn, int* ix, float* w) {
    const float a = -0.75f;
    float xf = floorf(xs);
    int x0 = (int)xf;
    float t = xs - xf;
#pragma unroll
    for (int j = -1; j <= 2; j++) {
        float d = fabsf(t - (float)j);
        float ww;
        if (d < 1.0f)      ww = ((a + 2.0f) * d - (a + 3.0f)) * d * d + 1.0f;
        else if (d < 2.0f) ww = ((a * d - 5.0f * a) * d + 8.0f * a) * d - 4.0f * a;
        else               ww = 0.0f;
        int xi = x0 + j;
        xi = xi < 0 ? 0 : (xi > pn - 1 ? pn - 1 : xi);
        ix[j + 1] = xi;
        w[j + 1]  = ww;
    }
}

// ---------------------------------------------------------------------------
// MFMA conv: dst = src - (0.5*h + 0.5*(conv3x3(h)+bias)), h = bicubic
// upsample, fp16-split into LDS, consumed by 16x16x32 f16 MFMA 3-chains
// (r7-verified fragment convention; r9 LDS window tables; r10 512x512 shape).
template <int PN, int PN_NEXT>
__global__ __launch_bounds__(512) void conv_mfma_kernel(const u64_t* __restrict__ pk,
                                                        const float* __restrict__ emb,
                                                        const half_t* __restrict__ whi,
                                                        const half_t* __restrict__ wlo,
                                                        const float* __restrict__ bias,
                                                        const float* __restrict__ src,
                                                        float* __restrict__ dst,
                                                        float* __restrict__ zp) {
    constexpr int IYB = (PN <= 4) ? PN : 6;   // iy tap band (span<=5 here)
    const int t    = threadIdx.x;
    const int lane = t & 63, col = lane & 15, quad = lane >> 4;
    const int wid  = t >> 6;                  // 0..7
    const int Nt   = wid >> 1, mt = wid & 1;
    const int ty   = Nt >> 1, xh = Nt & 1;    // ty 0..1
    const int yt   = blockIdx.x & 15, b = blockIdx.x >> 4;
    const int y0   = yt * 2;

    __shared__ half8 Hhi8[544], Hlo8[544];    // 4*34*32 halves = 8704 B each
    __shared__ float cache[IYB][PN][32];      // emb rows, ch-minor
    __shared__ int   riy[4][4];               // iy - iy_lo per staged row
    __shared__ float rwy[4][4];
    __shared__ int   cxs[34][4];              // col windows (gx = cl-1)
    __shared__ float cws[34][4];
    half_t* Hhi = (half_t*)Hhi8;
    half_t* Hlo = (half_t*)Hlo8;

    const float scale = (float)PN / (float)HH;
    int iy_lo = 0;
    if (PN > 4) {
        int lo = (int)floorf(((float)(y0 - 1) + 0.5f) * scale - 0.5f) - 1;
        lo = lo < 0 ? 0 : lo;
        lo = lo > PN - IYB ? PN - IYB : lo;
        iy_lo = lo;
    }

    // emb gather -> cache (float4 per 4ch; winner idx straight from pk, L2)
    const u64_t* pkb = pk + b * PN * PN;
    for (int i = t; i < IYB * PN * 8; i += 512) {
        int chg = i & 7, cell = i >> 3;
        int ix = cell % PN, iyb = cell / PN;
        int idx = (int)(unsigned)(pkb[(iy_lo + iyb) * PN + ix] & 0xFFFFFFFFull);
        *(float4*)&cache[iyb][ix][chg * 4] =
            *(const float4*)(emb + (size_t)idx * CH + chg * 4);
    }
    // bicubic window tables (disjoint thread ranges, concurrent with gather)
    if (t < 4) {
        int iy[4]; float wy[4];
        cubic_w(((float)(y0 - 1 + t) + 0.5f) * scale - 0.5f, PN, iy, wy);
#pragma unroll
        for (int a = 0; a < 4; a++) { riy[t][a] = iy[a] - iy_lo; rwy[t][a] = wy[a]; }
    }
    if (t >= 64 && t < 98) {
        int cl = t - 64;                  // col 0..33, gx = cl-1
        int ix[4]; float wx[4];
        cubic_w(((float)(cl - 1) + 0.5f) * scale - 0.5f, PN, ix, wx);
#pragma unroll
        for (int a = 0; a < 4; a++) { cxs[cl][a] = ix[a]; cws[cl][a] = wx[a]; }
    }
    __syncthreads();

    // bicubic staging -> H fp16-split (4 ch per iter; windows from LDS,
    // values & fma order bit-identical). 136 cells (4 rows x 34 cols) x 8.
    for (int i = t; i < 1088; i += 512) {
        int chg = i & 7, cell = i >> 3;
        int xs = cell % 34, row = cell / 34;     // row 0..3
        int gy = y0 - 1 + row, gx = xs - 1;
        float s0 = 0.f, s1 = 0.f, s2 = 0.f, s3 = 0.f;
        if ((unsigned)gy < 32u && (unsigned)gx < 32u) {
#pragma unroll
            for (int a = 0; a < 4; a++) {
                const int iyb = riy[row][a];
                const float wya = rwy[row][a];
                float r0 = 0.f, r1 = 0.f, r2 = 0.f, r3 = 0.f;
#pragma unroll
                for (int b2 = 0; b2 < 4; b2++) {
                    const float4 tv = *(const float4*)&cache[iyb][cxs[xs][b2]][chg * 4];
                    const float wxb = cws[xs][b2];
                    r0 = fmaf(tv.x, wxb, r0);
                    r1 = fmaf(tv.y, wxb, r1);
                    r2 = fmaf(tv.z, wxb, r2);
                    r3 = fmaf(tv.w, wxb, r3);
                }
                s0 = fmaf(r0, wya, s0);
                s1 = fmaf(r1, wya, s1);
                s2 = fmaf(r2, wya, s2);
                s3 = fmaf(r3, wya, s3);
            }
        }
        const int ho = cell * 32 + chg * 4;
        half_t h, l;
        split2(s0, &h, &l); Hhi[ho + 0] = h; Hlo[ho + 0] = l;
        split2(s1, &h, &l); Hhi[ho + 1] = h; Hlo[ho + 1] = l;
        split2(s2, &h, &l); Hhi[ho + 2] = h; Hlo[ho + 2] = l;
        split2(s3, &h, &l); Hhi[ho + 3] = h; Hlo[ho + 3] = l;
    }
    __syncthreads();

    // 9-tap MFMA accumulation; C-init = bias per output row (co)
    const float4 bv = *(const float4*)(bias + mt * 16 + quad * 4);
    floatx4 acc = {bv.x, bv.y, bv.z, bv.w};
#pragma unroll
    for (int tau = 0; tau < 9; tau++) {
        const int dy = tau / 3, dx = tau % 3;
        const int woff = (mt * 9 + tau) * 512 + quad * 128 + col * 8;
        const half8 wh = *(const half8*)(whi + woff);
        const half8 wl = *(const half8*)(wlo + woff);
        const int hoff = ((ty + dy) * 34 + xh * 16 + dx + col) * 32 + quad * 8;
        const half8 hh = *(const half8*)(Hhi + hoff);
        const half8 hl = *(const half8*)(Hlo + hoff);
        acc = __builtin_amdgcn_mfma_f32_16x16x32_f16(wh, hh, acc, 0, 0, 0);
        acc = __builtin_amdgcn_mfma_f32_16x16x32_f16(wh, hl, acc, 0, 0, 0);
        acc = __builtin_amdgcn_mfma_f32_16x16x32_f16(wl, hh, acc, 0, 0, 0);
    }

    // epilogue: residual + store; lane owns pix (y0+ty, xh*16+col), 4 co's
    const int x = xh * 16 + col, y = y0 + ty;
    const int hcell = ((ty + 1) * 34 + (x + 1)) * 32;
    float pv[4];
#pragma unroll
    for (int r = 0; r < 4; r++) {
        const int c = mt * 16 + quad * 4 + r;
        const float hc = (float)Hhi[hcell + c] + (float)Hlo[hcell + c];
        const size_t off = (((size_t)(b * CH + c)) * HH + y) * HH + x;
        const float dv = src[off] - (0.5f * hc + 0.5f * acc[r]);
        dst[off] = dv;
        pv[r] = dv;
    }

    if constexpr (PN_NEXT != 0) {
        constexpr int PSP = 32 / PN_NEXT;        // 16/8/4/2 (<=16: in-wave x)
#pragma unroll
        for (int m = 1; m < PSP; m <<= 1)        // col bits only, stays in quad
#pragma unroll
            for (int r = 0; r < 4; r++) pv[r] += __shfl_xor(pv[r], m, 64);
        if ((col & (PSP - 1)) == 0) {
            const int wx = x / PSP, wy = y / PSP;
#pragma unroll
            for (int r = 0; r < 4; r++) {
                const int c = mt * 16 + quad * 4 + r;
                atomicAdd(zp + ((size_t)((b * PN_NEXT + wy) * PN_NEXT + wx)) * CH + c,
                          pv[r]);
            }
        }
    }
}

// ---------------------------------------------------------------------------
// hits bincount over all scales' packed winners (multi-block, parallel —
// r3 lesson: single-block LDS-hist finalize was a 60us serial tail; r13
// lesson: last-block-done merge cost ~5us in device fences — keep separate)
__global__ __launch_bounds__(256) void bincount_kernel(const u64_t* __restrict__ pk,
                                                       float* __restrict__ hits, int n) {
    int i = blockIdx.x * 256 + threadIdx.x;
    if (i < n) {
        int idx = (int)(unsigned)(pk[i] & 0xFFFFFFFFull);
        atomicAdd(&hits[idx], 1.0f);
    }
}

// ---------------------------------------------------------------------------
// perplexity + loss finalize (single block; reads only 4096-entry hist +
// 1024 lacc partials = 20 KB)
__global__ __launch_bounds__(256) void finalize_kernel(const float* __restrict__ hits,
                                                       const float* __restrict__ laccp,
                                                       float* __restrict__ outs) {
    __shared__ float sh[256];
    int t = threadIdx.x;
    // total = NROWS_TOTAL exactly (each row contributes one hit)
    const float tot = (float)NROWS_TOTAL;
    float ent = 0.f;
    for (int v = t; v < VV; v += 256) {
        float p = hits[v] / tot;
        ent += p * logf(p + 1e-10f);
    }
    sh[t] = ent;
    __syncthreads();
    for (int o = 128; o > 0; o >>= 1) {
        if (t < o) sh[t] += sh[t + o];
        __syncthreads();
    }
    float entT = sh[0];            // valid for all after the synced tree
    __syncthreads();
    float ls = 0.f;
    for (int i = t; i < 1024; i += 256) ls += laccp[i];
    sh[t] = ls;
    __syncthreads();
    for (int o = 128; o > 0; o >>= 1) {
        if (t < o) sh[t] += sh[t + o];
        __syncthreads();
    }
    if (t == 0) {
        // loss = SN*(1+BETA)*mean(f^2) = 7.5 * sumsq / 1048576  (f_hat stays 0)
        outs[0] = 7.5f * sh[0] * (1.0f / (float)FELEMS);
        outs[1] = expf(-entT);
    }
}

// ---------------------------------------------------------------------------
extern "C" void kernel_launch(void* const* d_in, const int* in_sizes, int n_in,
                              void* d_out, int out_size, void* d_ws, size_t ws_size,
                              hipStream_t stream) {
    const float* f   = (const float*)d_in[0];   // (32,32,32,32)
    const float* emb = (const float*)d_in[1];   // (4096,32)
    const float* phw = (const float*)d_in[2];   // (4,32,32,3,3)
    const float* phb = (const float*)d_in[3];   // (4,32)
    float* out = (float*)d_out;                 // f_hat (1048576) + loss + perplexity

    float* ws      = (float*)d_ws;
    float* hits    = ws;                              // [0, 4096)
    float* laccp   = ws + 4096;                       // [4096, 5120) partials
    u64_t* pkbase  = (u64_t*)(ws + 8448);             // 43680 u64 -> [8448, 95808)
    float* frest   = ws + 95808;                      // [95808, 1144384)
    half_t* zhi    = (half_t*)(ws + 1144384);         // si=0 z-split (1024 used)
    half_t* zlo    = (half_t*)(ws + 1275456);
    float* nesqh   = ws + 1537600;                    // [1537600, 1541696)
    half_t* ehi    = (half_t*)(ws + 2590272);         // 131072 halves
    half_t* elo    = (half_t*)(ws + 2655808);         // ends 2721344
    float* zp      = ws + 2721344;                    // 348160 f -> ends 3069504
    half_t* whi    = (half_t*)(ws + 3069504);         // 36864 halves
    half_t* wlo    = (half_t*)(ws + 3087936);         // ends 3106368 (12.4 MB)

    // zp slices (zeroed once in prep; each written by exactly one conv)
    float* zp1 = zp;            // PN_NEXT=2:  4096
    float* zp2 = zp + 4096;     // PN_NEXT=4:  16384
    float* zp3 = zp + 20480;    // PN_NEXT=8:  65536
    float* zp4 = zp + 86016;    // PN_NEXT=16: 262144 -> total 348160

    prep_kernel<<<1024, 256, 0, stream>>>(f, emb, phw, whi, wlo, ehi, elo, nesqh,
                                          hits, laccp, zhi, zlo, pkbase, zp, out);

    const int pkoff[6] = {0, 32, 160, 672, 2720, 10912};
    const size_t WFP = 9216;                          // halves per phi frag-pack

    // si=0 (pn=1, sel=0)
    argmin_stage<1, 16><<<dim3(2, 16), 256, 0, stream>>>(zhi, zlo, ehi, elo, nesqh,
                                                         pkbase + pkoff[0]);
    conv_mfma_kernel<1, 2><<<512, 512, 0, stream>>>(pkbase + pkoff[0], emb,
                                                    whi + 0 * WFP, wlo + 0 * WFP,
                                                    phb + 0 * CH, f, frest, zp1);

    // si=1 (pn=2, sel=0)
    argmin_zp<1, 16, 2><<<dim3(8, 16), 256, 0, stream>>>(zp1, ehi, elo, nesqh,
                                                         pkbase + pkoff[1]);
    conv_mfma_kernel<2, 4><<<512, 512, 0, stream>>>(pkbase + pkoff[1], emb,
                                                    whi + 0 * WFP, wlo + 0 * WFP,
                                                    phb + 0 * CH, frest, frest, zp2);

    // si=2 (pn=4, sel=1)
    argmin_zp<1, 16, 4><<<dim3(32, 16), 256, 0, stream>>>(zp2, ehi, elo, nesqh,
                                                          pkbase + pkoff[2]);
    conv_mfma_kernel<4, 8><<<512, 512, 0, stream>>>(pkbase + pkoff[2], emb,
                                                    whi + 1 * WFP, wlo + 1 * WFP,
                                                    phb + 1 * CH, frest, frest, zp3);

    // si=3 (pn=8, sel=2)
    argmin_zp<1, 8, 8><<<dim3(128, 8), 256, 0, stream>>>(zp3, ehi, elo, nesqh,
                                                         pkbase + pkoff[3]);
    conv_mfma_kernel<8, 16><<<512, 512, 0, stream>>>(pkbase + pkoff[3], emb,
                                                     whi + 2 * WFP, wlo + 2 * WFP,
                                                     phb + 2 * CH, frest, frest, zp4);

    // si=4 (pn=16, sel=3): r7-proven config (grid (256,4), RT=2)
    argmin_zp<2, 4, 16><<<dim3(256, 4), 256, 0, stream>>>(zp4, ehi, elo, nesqh,
                                                          pkbase + pkoff[4]);
    conv_mfma_kernel<16, 0><<<512, 512, 0, stream>>>(pkbase + pkoff[4], emb,
                                                     whi + 3 * WFP, wlo + 3 * WFP,
                                                     phb + 3 * CH, frest, frest, nullptr);

    // si=5 (pn=32, sel=3): fused identity-pool argmin (r7-proven (512,2))
    argmin5_fused<<<dim3(512, 2), 256, 0, stream>>>(frest, ehi, elo, nesqh,
                                                    pkbase + pkoff[5]);

    bincount_kernel<<<(NROWS_TOTAL + 255) / 256, 256, 0, stream>>>(pkbase, hits, NROWS_TOTAL);
    finalize_kernel<<<1, 256, 0, stream>>>(hits, laccp, out + (out_size - 2));
}